// Round 11
// baseline (5690.121 us; speedup 1.0000x reference)
//
#include <hip/hip_runtime.h>
#include <math.h>

#define NDIM 4096
#define DDIM 1024
#define TSTEPS 1024
#define NWG 128
#define NHEAT 64     // DVFS heater WGs (register-only FMA spin)
#define NTHR 64      // ONE wave per WG: zero intra-block barriers
#define COLSPW 32    // NDIM / NWG; 2 lanes per column
#define HSTR 1028    // history stride: 4-way instead of 32-way bank aliasing
#define CJL 1024
#define SMEM_BYTES ((COLSPW * HSTR + CJL) * 4)

// ---------------- global min/max of attn over all B*N ----------------
__global__ __launch_bounds__(256) void k_minmax(const float* __restrict__ attn, int n,
                                                float* __restrict__ mm) {
  __shared__ float smin[4], smax[4];
  float vmin = INFINITY, vmax = -INFINITY;
  for (int i = threadIdx.x; i < n; i += 256) {
    float a = attn[i];
    vmin = fminf(vmin, a);
    vmax = fmaxf(vmax, a);
  }
#pragma unroll
  for (int m = 32; m >= 1; m >>= 1) {
    vmin = fminf(vmin, __shfl_xor(vmin, m, 64));
    vmax = fmaxf(vmax, __shfl_xor(vmax, m, 64));
  }
  if ((threadIdx.x & 63) == 0) { smin[threadIdx.x >> 6] = vmin; smax[threadIdx.x >> 6] = vmax; }
  __syncthreads();
  if (threadIdx.x == 0) {
    mm[0] = fminf(fminf(smin[0], smin[1]), fminf(smin[2], smin[3]));
    mm[1] = fmaxf(fmaxf(smax[0], smax[1]), fmaxf(smax[2], smax[3]));
  }
}

// ---------------- per-row normalize (batch 0) + rnorm ----------------
__global__ __launch_bounds__(256) void k_prep(const float* __restrict__ X,
                                              const float* __restrict__ attn,
                                              const float* __restrict__ mm,
                                              float* __restrict__ Xn,
                                              float* __restrict__ rnorm) {
  __shared__ float sp[4];
  __shared__ float s_norm;
  const int tid = threadIdx.x;
  const int row = blockIdx.x;
  const float* xr = X + (size_t)row * DDIM;
  float4 v = *(const float4*)(xr + tid * 4);
  float ss = v.x * v.x + v.y * v.y + v.z * v.z + v.w * v.w;
#pragma unroll
  for (int m = 32; m >= 1; m >>= 1) ss += __shfl_xor(ss, m, 64);
  if ((tid & 63) == 0) sp[tid >> 6] = ss;
  __syncthreads();
  if (tid == 0) {
    float tot = (sp[0] + sp[1]) + (sp[2] + sp[3]);
    s_norm = sqrtf(tot);
    float amin = mm[0], amax = mm[1];
    float t1 = amax - attn[row];           // == (-a) - rmin
    rnorm[row] = (t1 + 1e-6f) / (amax - amin);
  }
  __syncthreads();
  float nrm = s_norm;
  float4 o;
  o.x = v.x / nrm; o.y = v.y / nrm; o.z = v.z / nrm; o.w = v.w / nrm;
  *(float4*)(Xn + (size_t)row * DDIM + tid * 4) = o;
}

// ---------------- S = Xn * Xn^T  (f32, vector ALU) ----------------
__global__ __launch_bounds__(256) void k_gemm(const float* __restrict__ Xn,
                                              float* __restrict__ S) {
  __shared__ float As[16][68];
  __shared__ float Bs[16][68];
  const int tid = threadIdx.x;
  const int by = blockIdx.x >> 6, bx = blockIdx.x & 63;
  const int i0 = by << 6, j0 = bx << 6;
  const int tx = tid & 15, ty = tid >> 4;
  const int lr = tid >> 2, lk = (tid & 3) << 2;
  float acc[4][4] = {};
  const float* Ap = Xn + (size_t)(i0 + lr) * DDIM + lk;
  const float* Bp = Xn + (size_t)(j0 + lr) * DDIM + lk;
  for (int k0 = 0; k0 < DDIM; k0 += 16) {
    float4 av = *(const float4*)(Ap + k0);
    float4 bv = *(const float4*)(Bp + k0);
    __syncthreads();
    As[lk + 0][lr] = av.x; As[lk + 1][lr] = av.y; As[lk + 2][lr] = av.z; As[lk + 3][lr] = av.w;
    Bs[lk + 0][lr] = bv.x; Bs[lk + 1][lr] = bv.y; Bs[lk + 2][lr] = bv.z; Bs[lk + 3][lr] = bv.w;
    __syncthreads();
#pragma unroll
    for (int k = 0; k < 16; ++k) {
      float4 a = *(const float4*)&As[k][ty << 2];
      float4 b = *(const float4*)&Bs[k][tx << 2];
      acc[0][0] = fmaf(a.x, b.x, acc[0][0]); acc[0][1] = fmaf(a.x, b.y, acc[0][1]);
      acc[0][2] = fmaf(a.x, b.z, acc[0][2]); acc[0][3] = fmaf(a.x, b.w, acc[0][3]);
      acc[1][0] = fmaf(a.y, b.x, acc[1][0]); acc[1][1] = fmaf(a.y, b.y, acc[1][1]);
      acc[1][2] = fmaf(a.y, b.z, acc[1][2]); acc[1][3] = fmaf(a.y, b.w, acc[1][3]);
      acc[2][0] = fmaf(a.z, b.x, acc[2][0]); acc[2][1] = fmaf(a.z, b.y, acc[2][1]);
      acc[2][2] = fmaf(a.z, b.z, acc[2][2]); acc[2][3] = fmaf(a.z, b.w, acc[2][3]);
      acc[3][0] = fmaf(a.w, b.x, acc[3][0]); acc[3][1] = fmaf(a.w, b.y, acc[3][1]);
      acc[3][2] = fmaf(a.w, b.z, acc[3][2]); acc[3][3] = fmaf(a.w, b.w, acc[3][3]);
    }
  }
#pragma unroll
  for (int m = 0; m < 4; ++m) {
    float4 o;
    o.x = acc[m][0]; o.y = acc[m][1]; o.z = acc[m][2]; o.w = acc[m][3];
    *(float4*)(S + (size_t)(i0 + (ty << 2) + m) * NDIM + j0 + (tx << 2)) = o;
  }
}

// ---------------- persistent greedy-DPP scan (single-wave WGs) ----------------
__device__ __forceinline__ void vimerge(float& v, int& id, float v2, int id2) {
  if (v2 > v || (v2 == v && id2 < id)) { v = v2; id = id2; }
}

// monotone float->u32; low field prefers smaller index on ties; never 0.
__device__ __forceinline__ unsigned long long packvi(float v, int idx) {
  unsigned u = __float_as_uint(v);
  u = (u & 0x80000000u) ? ~u : (u | 0x80000000u);
  return ((unsigned long long)u << 32) | (unsigned)(NDIM - 1 - idx);
}

__device__ __forceinline__ unsigned long long ag_load64(const unsigned long long* p) {
  return __hip_atomic_load(p, __ATOMIC_RELAXED, __HIP_MEMORY_SCOPE_AGENT);
}
__device__ __forceinline__ void ag_store64(unsigned long long* p, unsigned long long v) {
  __hip_atomic_store(p, v, __ATOMIC_RELAXED, __HIP_MEMORY_SCOPE_AGENT);
}
__device__ __forceinline__ void ag_storef(float* p, float v) {
  __hip_atomic_store(p, v, __ATOMIC_RELAXED, __HIP_MEMORY_SCOPE_AGENT);
}
__device__ __forceinline__ unsigned ag_load32(const unsigned* p) {
  return __hip_atomic_load(p, __ATOMIC_RELAXED, __HIP_MEMORY_SCOPE_AGENT);
}
__device__ __forceinline__ void ag_store32(unsigned* p, unsigned v) {
  __hip_atomic_store(p, v, __ATOMIC_RELAXED, __HIP_MEMORY_SCOPE_AGENT);
}

// slots[i][wg] = { packvi(partial max), eis_bits | (1<<32) }  (16B aligned)
__global__ __launch_bounds__(NTHR) void k_scan(const float* __restrict__ S,
                                               const float* __restrict__ rnorm,
                                               float* __restrict__ cisT,               // [N][T], pre-zeroed
                                               unsigned long long* __restrict__ slots, // [T][NWG][2], pre-zeroed
                                               int* __restrict__ sel,
                                               unsigned* __restrict__ done) {
  const int lane = threadIdx.x;          // 0..63, one wave
  const int wg = blockIdx.x;

  if (wg >= NWG) {
    // ---- DVFS heater: register-only FMA spin until the scan finishes ----
    float acc = 1.0f + (float)lane;
    for (;;) {
#pragma unroll
      for (int r = 0; r < 256; ++r) acc = fmaf(acc, 1.0000001f, 1e-7f);
      asm volatile("" :: "v"(acc));  // keep live, no DCE (rule #17)
      if (ag_load32(done) != 0) break;
    }
    return;
  }

  extern __shared__ float smem[];
  float* hist = smem;                    // [COLSPW][HSTR]
  float* cjL = smem + COLSPW * HSTR;     // [CJL]

  const int col = lane >> 1;
  const int par = lane & 1;
  const int n = wg * COLSPW + col;
  float* hrow = hist + col * HSTR;

  // zero history + cjL (zero tails make uniform trip counts exact)
  for (int idx = lane * 4; idx < COLSPW * HSTR + CJL; idx += NTHR * 4) {
    float4 z = {0.f, 0.f, 0.f, 0.f};
    *(float4*)(smem + idx) = z;
  }

  // init di2s on even lanes; odd lanes carry -inf
  float di2s = -INFINITY, rn = 0.f;
  if (par == 0) {
    rn = rnorm[n];
    di2s = (rn * S[(size_t)n * NDIM + n]) * rn;
  }
  {
    float v = di2s;
    int id = (par == 0) ? n : 0x7FFFFFFF;
#pragma unroll
    for (int m = 2; m <= 32; m <<= 1)
      vimerge(v, id, __shfl_xor(v, m, 64), __shfl_xor(id, m, 64));
    vimerge(v, id, __shfl_xor(v, 1, 64), __shfl_xor(id, 1, 64));
    if (lane == 0) {
      ag_store64(&slots[2 * wg], packvi(v, id));
      ag_store64(&slots[2 * wg + 1], 1ull << 32);  // dummy eis, marker set
    }
  }

  bool dead = false;
  for (int i = 0;; ++i) {
    // ---- poll step-i slot pairs: 4 independent u64 loads per lane ----
    // NOTE: the s_waitcnt vmcnt(0) the compiler emits to consume these loads
    // also retires our OLDER eis/slot stores (gfx9 vmcnt retires in issue
    // order) -> flag-implies-data holds with no explicit drain.
    const unsigned long long* base = slots + (size_t)i * NWG * 2;
    unsigned long long a0 = 0, b0 = 0, a1 = 0, b1 = 0;
    if (!dead) {
      int spins = 0;
      for (;;) {
        a0 = ag_load64(base + 2 * lane);
        b0 = ag_load64(base + 2 * lane + 1);
        a1 = ag_load64(base + 2 * (64 + lane));
        b1 = ag_load64(base + 2 * (64 + lane) + 1);
        if (__all((a0 != 0) && (b0 != 0) && (a1 != 0) && (b1 != 0))) break;
        if (++spins > (1 << 15)) { dead = true; break; }
      }
    }
    unsigned long long v = a0 > a1 ? a0 : a1;
#pragma unroll
    for (int m = 32; m >= 1; m >>= 1) {
      unsigned long long o = __shfl_xor(v, m, 64);
      if (o > v) v = o;
    }
    // winner's carried eis (cj element i-1)
    float myeis = (a0 == v) ? __uint_as_float((unsigned)b0)
                            : __uint_as_float((unsigned)b1);
    unsigned long long hitmask = __ballot((a0 == v) || (a1 == v));
    const int srcl = (int)(__ffsll((long long)hitmask) - 1);
    const float eisw = __shfl(myeis, srcl, 64);

    const int j = (NDIM - 1 - (int)(unsigned)(v & 0xFFFFFFFFu)) & (NDIM - 1);
    unsigned uu = (unsigned)(v >> 32);
    uu = (uu & 0x80000000u) ? (uu ^ 0x80000000u) : ~uu;
    const float dj = __uint_as_float(uu);
    if (wg == 0 && lane == 0) sel[i] = j;
    if (i == TSTEPS - 1) {
      if (wg == 0 && lane == 0) ag_store32(done, 1u);  // release heaters
      break;
    }

    // j-dependent inputs (issue early; consumed after contraction)
    float rj = 0.f, kjS = 0.f;
    if (par == 0) { rj = rnorm[j]; kjS = S[(size_t)j * NDIM + n]; }

    // ---- stage cj[0:i-2] from cisT as batched volleys; cj[i-1] from slot ----
    const unsigned long long* q = (const unsigned long long*)(cisT + (size_t)j * TSTEPS);
    const int nv = (i >= 1) ? ((i - 1 + 127) >> 7) : 0;  // 64-lane x 8B volleys
    unsigned long long d0, d1, d2, d3, d4, d5, d6, d7;
    if (nv > 0) d0 = ag_load64(q + 0 * 64 + lane);
    if (nv > 1) d1 = ag_load64(q + 1 * 64 + lane);
    if (nv > 2) d2 = ag_load64(q + 2 * 64 + lane);
    if (nv > 3) d3 = ag_load64(q + 3 * 64 + lane);
    if (nv > 4) d4 = ag_load64(q + 4 * 64 + lane);
    if (nv > 5) d5 = ag_load64(q + 5 * 64 + lane);
    if (nv > 6) d6 = ag_load64(q + 6 * 64 + lane);
    if (nv > 7) d7 = ag_load64(q + 7 * 64 + lane);
    unsigned long long* cjq = (unsigned long long*)cjL;
    if (nv > 0) cjq[0 * 64 + lane] = d0;
    if (nv > 1) cjq[1 * 64 + lane] = d1;
    if (nv > 2) cjq[2 * 64 + lane] = d2;
    if (nv > 3) cjq[3 * 64 + lane] = d3;
    if (nv > 4) cjq[4 * 64 + lane] = d4;
    if (nv > 5) cjq[5 * 64 + lane] = d5;
    if (nv > 6) cjq[6 * 64 + lane] = d6;
    if (nv > 7) cjq[7 * 64 + lane] = d7;
    if (i >= 1 && lane == 0) cjL[i - 1] = eisw;  // freshest element from slot

    // ---- contraction s = sum_{t<i} cj[t] * hist[col][t] (LDS only) ----
    float s0 = 0.f, s1 = 0.f, s2 = 0.f, s3 = 0.f;
    const int nk = (i + 7) >> 3;  // per-lane b128 chunks (2 lanes/col interleave)
    for (int k = 0; k < nk; ++k) {
      const int t4 = (k * 2 + par) * 4;
      float4 h = *(const float4*)(hrow + t4);
      float4 c = *(const float4*)(cjL + t4);
      s0 = fmaf(h.x, c.x, s0);
      s1 = fmaf(h.y, c.y, s1);
      s2 = fmaf(h.z, c.z, s2);
      s3 = fmaf(h.w, c.w, s3);
    }
    float s = (s0 + s1) + (s2 + s3);
    s += __shfl_xor(s, 1, 64);  // pair-sum -> even lane has full dot

    float eis = 0.f;
    if (par == 0) {
      float kjn = (rj * kjS) * rn;
      eis = (kjn - s) / sqrtf(dj);
      float d = __fsub_rn(di2s, __fmul_rn(eis, eis));
      if (n == j) d = -INFINITY;
      di2s = d;
      hrow[i] = eis;                                  // LDS history
      ag_storef(cisT + (size_t)n * TSTEPS + i, eis);  // publish (drained at next poll)
    }

    // ---- partial argmax for step i+1 + carried eis of the candidate ----
    float pv = di2s;
    int pid = (par == 0) ? n : 0x7FFFFFFF;
#pragma unroll
    for (int m = 2; m <= 32; m <<= 1)
      vimerge(pv, pid, __shfl_xor(pv, m, 64), __shfl_xor(pid, m, 64));
    vimerge(pv, pid, __shfl_xor(pv, 1, 64), __shfl_xor(pid, 1, 64));
    const float ecar = __shfl(eis, (pid - wg * COLSPW) * 2, 64);
    if (lane == 0) {
      unsigned long long* sl = slots + ((size_t)(i + 1) * NWG + wg) * 2;
      ag_store64(sl, packvi(pv, pid));
      ag_store64(sl + 1, (unsigned long long)__float_as_uint(ecar) | (1ull << 32));
    }
    // (no explicit vmcnt drain: next poll's vmcnt(0) retires older stores first)
  }
}

extern "C" void kernel_launch(void* const* d_in, const int* in_sizes, int n_in,
                              void* d_out, int out_size, void* d_ws, size_t ws_size,
                              hipStream_t stream) {
  const float* X = (const float*)d_in[0];      // [2,4096,1024] f32
  const float* attn = (const float*)d_in[1];   // [2,4096] f32
  int* sel = (int*)d_out;                      // [1024] int32
  char* ws = (char*)d_ws;

  float* mm = (float*)ws;                                    // 8 B
  unsigned* done = (unsigned*)(ws + 2048);                   // 4 B
  float* rnorm = (float*)(ws + 4096);                        // 16 KB
  char* big = ws + 65536;
  float* Xn = (float*)big;                                   // 16 MB
  float* S = (float*)(big + (size_t)16 * 1024 * 1024);       // 64 MB
  float* cisT = (float*)(big + (size_t)80 * 1024 * 1024);    // 16 MB
  unsigned long long* slots =
      (unsigned long long*)(big + (size_t)96 * 1024 * 1024); // 2 MB

  const int nattn = in_sizes[1];  // 8192

  hipFuncSetAttribute((const void*)k_scan,
                      hipFuncAttributeMaxDynamicSharedMemorySize, SMEM_BYTES);

  hipMemsetAsync(done, 0, 64, stream);
  hipMemsetAsync(slots, 0, (size_t)TSTEPS * NWG * 2 * sizeof(unsigned long long), stream);
  hipMemsetAsync(cisT, 0, (size_t)NDIM * TSTEPS * sizeof(float), stream);
  k_minmax<<<1, 256, 0, stream>>>(attn, nattn, mm);
  k_prep<<<NDIM, 256, 0, stream>>>(X, attn, mm, Xn, rnorm);
  k_gemm<<<64 * 64, 256, 0, stream>>>(Xn, S);
  k_scan<<<NWG + NHEAT, NTHR, SMEM_BYTES, stream>>>(S, rnorm, cisT, slots, sel, done);
}

// Round 12
// 4500.160 us; speedup vs baseline: 1.2644x; 1.2644x over previous
//
#include <hip/hip_runtime.h>
#include <math.h>

#define NDIM 4096
#define DDIM 1024
#define TSTEPS 1024
#define NWG 128
#define NTHR 64      // ONE wave per WG: zero intra-block barriers
#define COLSPW 32    // NDIM / NWG; 2 lanes per column
#define HSTR 1028    // history stride: 4-way instead of 32-way bank aliasing
#define CJL 1024
#define SMEM_BYTES ((COLSPW * HSTR + CJL) * 4)

// ---------------- global min/max of attn over all B*N ----------------
__global__ __launch_bounds__(256) void k_minmax(const float* __restrict__ attn, int n,
                                                float* __restrict__ mm) {
  __shared__ float smin[4], smax[4];
  float vmin = INFINITY, vmax = -INFINITY;
  for (int i = threadIdx.x; i < n; i += 256) {
    float a = attn[i];
    vmin = fminf(vmin, a);
    vmax = fmaxf(vmax, a);
  }
#pragma unroll
  for (int m = 32; m >= 1; m >>= 1) {
    vmin = fminf(vmin, __shfl_xor(vmin, m, 64));
    vmax = fmaxf(vmax, __shfl_xor(vmax, m, 64));
  }
  if ((threadIdx.x & 63) == 0) { smin[threadIdx.x >> 6] = vmin; smax[threadIdx.x >> 6] = vmax; }
  __syncthreads();
  if (threadIdx.x == 0) {
    mm[0] = fminf(fminf(smin[0], smin[1]), fminf(smin[2], smin[3]));
    mm[1] = fmaxf(fmaxf(smax[0], smax[1]), fmaxf(smax[2], smax[3]));
  }
}

// ---------------- per-row normalize (batch 0) + rnorm ----------------
__global__ __launch_bounds__(256) void k_prep(const float* __restrict__ X,
                                              const float* __restrict__ attn,
                                              const float* __restrict__ mm,
                                              float* __restrict__ Xn,
                                              float* __restrict__ rnorm) {
  __shared__ float sp[4];
  __shared__ float s_norm;
  const int tid = threadIdx.x;
  const int row = blockIdx.x;
  const float* xr = X + (size_t)row * DDIM;
  float4 v = *(const float4*)(xr + tid * 4);
  float ss = v.x * v.x + v.y * v.y + v.z * v.z + v.w * v.w;
#pragma unroll
  for (int m = 32; m >= 1; m >>= 1) ss += __shfl_xor(ss, m, 64);
  if ((tid & 63) == 0) sp[tid >> 6] = ss;
  __syncthreads();
  if (tid == 0) {
    float tot = (sp[0] + sp[1]) + (sp[2] + sp[3]);
    s_norm = sqrtf(tot);
    float amin = mm[0], amax = mm[1];
    float t1 = amax - attn[row];           // == (-a) - rmin
    rnorm[row] = (t1 + 1e-6f) / (amax - amin);
  }
  __syncthreads();
  float nrm = s_norm;
  float4 o;
  o.x = v.x / nrm; o.y = v.y / nrm; o.z = v.z / nrm; o.w = v.w / nrm;
  *(float4*)(Xn + (size_t)row * DDIM + tid * 4) = o;
}

// ---------------- S = Xn * Xn^T  (f32, vector ALU) ----------------
__global__ __launch_bounds__(256) void k_gemm(const float* __restrict__ Xn,
                                              float* __restrict__ S) {
  __shared__ float As[16][68];
  __shared__ float Bs[16][68];
  const int tid = threadIdx.x;
  const int by = blockIdx.x >> 6, bx = blockIdx.x & 63;
  const int i0 = by << 6, j0 = bx << 6;
  const int tx = tid & 15, ty = tid >> 4;
  const int lr = tid >> 2, lk = (tid & 3) << 2;
  float acc[4][4] = {};
  const float* Ap = Xn + (size_t)(i0 + lr) * DDIM + lk;
  const float* Bp = Xn + (size_t)(j0 + lr) * DDIM + lk;
  for (int k0 = 0; k0 < DDIM; k0 += 16) {
    float4 av = *(const float4*)(Ap + k0);
    float4 bv = *(const float4*)(Bp + k0);
    __syncthreads();
    As[lk + 0][lr] = av.x; As[lk + 1][lr] = av.y; As[lk + 2][lr] = av.z; As[lk + 3][lr] = av.w;
    Bs[lk + 0][lr] = bv.x; Bs[lk + 1][lr] = bv.y; Bs[lk + 2][lr] = bv.z; Bs[lk + 3][lr] = bv.w;
    __syncthreads();
#pragma unroll
    for (int k = 0; k < 16; ++k) {
      float4 a = *(const float4*)&As[k][ty << 2];
      float4 b = *(const float4*)&Bs[k][tx << 2];
      acc[0][0] = fmaf(a.x, b.x, acc[0][0]); acc[0][1] = fmaf(a.x, b.y, acc[0][1]);
      acc[0][2] = fmaf(a.x, b.z, acc[0][2]); acc[0][3] = fmaf(a.x, b.w, acc[0][3]);
      acc[1][0] = fmaf(a.y, b.x, acc[1][0]); acc[1][1] = fmaf(a.y, b.y, acc[1][1]);
      acc[1][2] = fmaf(a.y, b.z, acc[1][2]); acc[1][3] = fmaf(a.y, b.w, acc[1][3]);
      acc[2][0] = fmaf(a.z, b.x, acc[2][0]); acc[2][1] = fmaf(a.z, b.y, acc[2][1]);
      acc[2][2] = fmaf(a.z, b.z, acc[2][2]); acc[2][3] = fmaf(a.z, b.w, acc[2][3]);
      acc[3][0] = fmaf(a.w, b.x, acc[3][0]); acc[3][1] = fmaf(a.w, b.y, acc[3][1]);
      acc[3][2] = fmaf(a.w, b.z, acc[3][2]); acc[3][3] = fmaf(a.w, b.w, acc[3][3]);
    }
  }
#pragma unroll
  for (int m = 0; m < 4; ++m) {
    float4 o;
    o.x = acc[m][0]; o.y = acc[m][1]; o.z = acc[m][2]; o.w = acc[m][3];
    *(float4*)(S + (size_t)(i0 + (ty << 2) + m) * NDIM + j0 + (tx << 2)) = o;
  }
}

// ---------------- persistent greedy-DPP scan (single-wave WGs) ----------------
__device__ __forceinline__ void vimerge(float& v, int& id, float v2, int id2) {
  if (v2 > v || (v2 == v && id2 < id)) { v = v2; id = id2; }
}

// monotone float->u32; low field prefers smaller index on ties; never 0.
__device__ __forceinline__ unsigned long long packvi(float v, int idx) {
  unsigned u = __float_as_uint(v);
  u = (u & 0x80000000u) ? ~u : (u | 0x80000000u);
  return ((unsigned long long)u << 32) | (unsigned)(NDIM - 1 - idx);
}

__device__ __forceinline__ unsigned long long ag_load64(const unsigned long long* p) {
  return __hip_atomic_load(p, __ATOMIC_RELAXED, __HIP_MEMORY_SCOPE_AGENT);
}
__device__ __forceinline__ void ag_store64(unsigned long long* p, unsigned long long v) {
  __hip_atomic_store(p, v, __ATOMIC_RELAXED, __HIP_MEMORY_SCOPE_AGENT);
}
__device__ __forceinline__ void ag_storef(float* p, float v) {
  __hip_atomic_store(p, v, __ATOMIC_RELAXED, __HIP_MEMORY_SCOPE_AGENT);
}

// slots[i][wg] = { packvi(partial max), eis_bits | (1<<32) }  (16B aligned)
__global__ __launch_bounds__(NTHR) void k_scan(const float* __restrict__ S,
                                               const float* __restrict__ rnorm,
                                               float* __restrict__ cisT,               // [N][T], pre-zeroed
                                               unsigned long long* __restrict__ slots, // [T][NWG][2], pre-zeroed
                                               int* __restrict__ sel) {
  extern __shared__ float smem[];
  float* hist = smem;                    // [COLSPW][HSTR]
  float* cjL = smem + COLSPW * HSTR;     // [CJL]

  const int lane = threadIdx.x;          // 0..63, one wave
  const int wg = blockIdx.x;
  const int col = lane >> 1;
  const int par = lane & 1;
  const int n = wg * COLSPW + col;
  float* hrow = hist + col * HSTR;

  // zero history + cjL (zero tails make uniform trip counts exact)
  for (int idx = lane * 4; idx < COLSPW * HSTR + CJL; idx += NTHR * 4) {
    float4 z = {0.f, 0.f, 0.f, 0.f};
    *(float4*)(smem + idx) = z;
  }

  // init di2s on even lanes; odd lanes carry -inf
  float di2s = -INFINITY, rn = 0.f;
  if (par == 0) {
    rn = rnorm[n];
    di2s = (rn * S[(size_t)n * NDIM + n]) * rn;
  }
  {
    float v = di2s;
    int id = (par == 0) ? n : 0x7FFFFFFF;
#pragma unroll
    for (int m = 2; m <= 32; m <<= 1)
      vimerge(v, id, __shfl_xor(v, m, 64), __shfl_xor(id, m, 64));
    vimerge(v, id, __shfl_xor(v, 1, 64), __shfl_xor(id, 1, 64));
    if (lane == 0) {
      ag_store64(&slots[2 * wg], packvi(v, id));
      ag_store64(&slots[2 * wg + 1], 1ull << 32);  // dummy eis, marker set
    }
  }

  bool dead = false;
  for (int i = 0;; ++i) {
    // ---- poll step-i slot pairs: 4 independent u64 loads per lane ----
    const unsigned long long* base = slots + (size_t)i * NWG * 2;
    unsigned long long a0 = 0, b0 = 0, a1 = 0, b1 = 0;
    if (!dead) {
      int spins = 0;
      for (;;) {
        a0 = ag_load64(base + 2 * lane);
        b0 = ag_load64(base + 2 * lane + 1);
        a1 = ag_load64(base + 2 * (64 + lane));
        b1 = ag_load64(base + 2 * (64 + lane) + 1);
        if (__all((a0 != 0) && (b0 != 0) && (a1 != 0) && (b1 != 0))) break;
        if (++spins > (1 << 15)) { dead = true; break; }
      }
    }
    unsigned long long v = a0 > a1 ? a0 : a1;
#pragma unroll
    for (int m = 32; m >= 1; m >>= 1) {
      unsigned long long o = __shfl_xor(v, m, 64);
      if (o > v) v = o;
    }
    // winner's carried eis (cj element i-1)
    float myeis = (a0 == v) ? __uint_as_float((unsigned)b0)
                            : __uint_as_float((unsigned)b1);
    unsigned long long hitmask = __ballot((a0 == v) || (a1 == v));
    const int srcl = (int)(__ffsll((long long)hitmask) - 1);
    const float eisw = __shfl(myeis, srcl, 64);

    const int j = (NDIM - 1 - (int)(unsigned)(v & 0xFFFFFFFFu)) & (NDIM - 1);
    unsigned uu = (unsigned)(v >> 32);
    uu = (uu & 0x80000000u) ? (uu ^ 0x80000000u) : ~uu;
    const float dj = __uint_as_float(uu);
    if (wg == 0 && lane == 0) sel[i] = j;
    if (i == TSTEPS - 1) break;

    // j-dependent inputs (issue early; consumed after contraction)
    float rj = 0.f, kjS = 0.f;
    if (par == 0) { rj = rnorm[j]; kjS = S[(size_t)j * NDIM + n]; }

    // ---- stage cj[0:i-2] from cisT as batched volleys; cj[i-1] from slot ----
    const unsigned long long* q = (const unsigned long long*)(cisT + (size_t)j * TSTEPS);
    const int nv = (i >= 1) ? ((i - 1 + 127) >> 7) : 0;  // 64-lane x 8B volleys
    unsigned long long d0, d1, d2, d3, d4, d5, d6, d7;
    if (nv > 0) d0 = ag_load64(q + 0 * 64 + lane);
    if (nv > 1) d1 = ag_load64(q + 1 * 64 + lane);
    if (nv > 2) d2 = ag_load64(q + 2 * 64 + lane);
    if (nv > 3) d3 = ag_load64(q + 3 * 64 + lane);
    if (nv > 4) d4 = ag_load64(q + 4 * 64 + lane);
    if (nv > 5) d5 = ag_load64(q + 5 * 64 + lane);
    if (nv > 6) d6 = ag_load64(q + 6 * 64 + lane);
    if (nv > 7) d7 = ag_load64(q + 7 * 64 + lane);
    unsigned long long* cjq = (unsigned long long*)cjL;
    if (nv > 0) cjq[0 * 64 + lane] = d0;
    if (nv > 1) cjq[1 * 64 + lane] = d1;
    if (nv > 2) cjq[2 * 64 + lane] = d2;
    if (nv > 3) cjq[3 * 64 + lane] = d3;
    if (nv > 4) cjq[4 * 64 + lane] = d4;
    if (nv > 5) cjq[5 * 64 + lane] = d5;
    if (nv > 6) cjq[6 * 64 + lane] = d6;
    if (nv > 7) cjq[7 * 64 + lane] = d7;
    if (i >= 1 && lane == 0) cjL[i - 1] = eisw;  // freshest element from slot

    // ---- contraction s = sum_{t<i} cj[t] * hist[col][t] (LDS only) ----
    float s0 = 0.f, s1 = 0.f, s2 = 0.f, s3 = 0.f;
    const int nk = (i + 7) >> 3;  // per-lane b128 chunks (2 lanes/col interleave)
    for (int k = 0; k < nk; ++k) {
      const int t4 = (k * 2 + par) * 4;
      float4 h = *(const float4*)(hrow + t4);
      float4 c = *(const float4*)(cjL + t4);
      s0 = fmaf(h.x, c.x, s0);
      s1 = fmaf(h.y, c.y, s1);
      s2 = fmaf(h.z, c.z, s2);
      s3 = fmaf(h.w, c.w, s3);
    }
    float s = (s0 + s1) + (s2 + s3);
    s += __shfl_xor(s, 1, 64);  // pair-sum -> even lane has full dot

    float eis = 0.f;
    if (par == 0) {
      float kjn = (rj * kjS) * rn;
      eis = (kjn - s) / sqrtf(dj);
      float d = __fsub_rn(di2s, __fmul_rn(eis, eis));
      if (n == j) d = -INFINITY;
      di2s = d;
      hrow[i] = eis;                                  // LDS history
      ag_storef(cisT + (size_t)n * TSTEPS + i, eis);  // publish (drained post-flag)
    }

    // ---- partial argmax for step i+1 + carried eis of the candidate ----
    float pv = di2s;
    int pid = (par == 0) ? n : 0x7FFFFFFF;
#pragma unroll
    for (int m = 2; m <= 32; m <<= 1)
      vimerge(pv, pid, __shfl_xor(pv, m, 64), __shfl_xor(pid, m, 64));
    vimerge(pv, pid, __shfl_xor(pv, 1, 64), __shfl_xor(pid, 1, 64));
    const float ecar = __shfl(eis, (pid - wg * COLSPW) * 2, 64);
    if (lane == 0) {
      unsigned long long* sl = slots + ((size_t)(i + 1) * NWG + wg) * 2;
      ag_store64(sl, packvi(pv, pid));
      ag_store64(sl + 1, (unsigned long long)__float_as_uint(ecar) | (1ull << 32));
    }
    // drain AFTER publish: guarantees this step's cisT stores are at LLC
    // before the NEXT flag we publish (readers of flag i+2 need element i).
    asm volatile("s_waitcnt vmcnt(0)" ::: "memory");
  }
}

extern "C" void kernel_launch(void* const* d_in, const int* in_sizes, int n_in,
                              void* d_out, int out_size, void* d_ws, size_t ws_size,
                              hipStream_t stream) {
  const float* X = (const float*)d_in[0];      // [2,4096,1024] f32
  const float* attn = (const float*)d_in[1];   // [2,4096] f32
  int* sel = (int*)d_out;                      // [1024] int32
  char* ws = (char*)d_ws;

  float* mm = (float*)ws;                                    // 8 B
  float* rnorm = (float*)(ws + 4096);                        // 16 KB
  char* big = ws + 65536;
  float* Xn = (float*)big;                                   // 16 MB
  float* S = (float*)(big + (size_t)16 * 1024 * 1024);       // 64 MB
  float* cisT = (float*)(big + (size_t)80 * 1024 * 1024);    // 16 MB
  unsigned long long* slots =
      (unsigned long long*)(big + (size_t)96 * 1024 * 1024); // 2 MB

  const int nattn = in_sizes[1];  // 8192

  hipFuncSetAttribute((const void*)k_scan,
                      hipFuncAttributeMaxDynamicSharedMemorySize, SMEM_BYTES);

  hipMemsetAsync(slots, 0, (size_t)TSTEPS * NWG * 2 * sizeof(unsigned long long), stream);
  hipMemsetAsync(cisT, 0, (size_t)NDIM * TSTEPS * sizeof(float), stream);
  k_minmax<<<1, 256, 0, stream>>>(attn, nattn, mm);
  k_prep<<<NDIM, 256, 0, stream>>>(X, attn, mm, Xn, rnorm);
  k_gemm<<<64 * 64, 256, 0, stream>>>(Xn, S);
  k_scan<<<NWG, NTHR, SMEM_BYTES, stream>>>(S, rnorm, cisT, slots, sel);
}